// Round 15
// baseline (304.136 us; speedup 1.0000x reference)
//
#include <hip/hip_runtime.h>
#include <stdint.h>

#define M_ 8192   // B*L
#define D_ 768
#define N_ 8192

typedef unsigned short u16;
typedef __attribute__((ext_vector_type(8))) unsigned short us8;
typedef __attribute__((ext_vector_type(8))) __bf16 bf16x8;
typedef __attribute__((ext_vector_type(4))) float f32x4;

__device__ __forceinline__ u16 f2bf(float f) {
  uint32_t u = __builtin_bit_cast(uint32_t, f);
  u += 0x7FFFu + ((u >> 16) & 1u);   // RNE
  return (u16)(u >> 16);
}

__device__ __forceinline__ void gload_lds16(const void* g, void* l) {
  __builtin_amdgcn_global_load_lds(
      (__attribute__((address_space(1))) void*)g,
      (__attribute__((address_space(3))) void*)l, 16, 0, 0);
}

// ------------- two-array f32 -> bf16 convert (both weights) -------------
__global__ __launch_bounds__(256)
void k_cvt2(const float* __restrict__ a, const float* __restrict__ b,
            u16* __restrict__ da, u16* __restrict__ db, int n4each) {
  int stride = gridDim.x * blockDim.x;
  for (int i = blockIdx.x * blockDim.x + threadIdx.x; i < 2 * n4each; i += stride) {
    const float* s = (i < n4each) ? a : b;
    u16* d = (i < n4each) ? da : db;
    int j = (i < n4each) ? i : i - n4each;
    float4 v = reinterpret_cast<const float4*>(s)[j];
    ushort4 o;
    o.x = f2bf(v.x); o.y = f2bf(v.y); o.z = f2bf(v.z); o.w = f2bf(v.w);
    reinterpret_cast<ushort4*>(d)[j] = o;
  }
}

// ---- Vt[d][n] = bf16(prior[n] * dic[n][d]) ----
__global__ __launch_bounds__(256)
void k_build_vt(const float* __restrict__ dic, const float* __restrict__ prior,
                u16* __restrict__ Vt) {
  __shared__ float t[32][33];
  const int n0 = blockIdx.x * 32, d0 = blockIdx.y * 32;
  const int tx = threadIdx.x, ty = threadIdx.y;
  #pragma unroll
  for (int i = ty; i < 32; i += 8)
    t[i][tx] = dic[(size_t)(n0 + i) * D_ + d0 + tx] * prior[n0 + i];
  __syncthreads();
  #pragma unroll
  for (int i = ty; i < 32; i += 8)
    Vt[(size_t)(d0 + i) * N_ + n0 + tx] = f2bf(t[tx][i]);
}

// ============ 256x256 NT bf16 S-GEMM — round-7 schedule (best measured) ====
// Cb = bf16(exp(acc*scale)), row-sums via LDS scratch -> 1 atomic/row/block.
__global__ __launch_bounds__(512, 2)
void k_gemm8(const u16* __restrict__ A, const u16* __restrict__ Bm,
             u16* __restrict__ Cb, float* __restrict__ Cf, float scale,
             long ldk, int K, int Ncols, int nbx) {
  extern __shared__ u16 ldsu[];   // 65536 u16 = 128 KiB: [buf2][mat2][16384]
  const int tid = threadIdx.x;
  const int lane = tid & 63, wid = tid >> 6;
  const int wr = wid >> 2, wc = wid & 3;
  const int L15 = lane & 15, L7 = lane & 7, g = lane >> 4;

  const int nwg = gridDim.x;
  const int bid = blockIdx.x;
  const int wg = ((nwg & 7) == 0) ? ((bid & 7) * (nwg >> 3) + (bid >> 3)) : bid;
  const int bx = wg % nbx, by = wg / nbx;
  const long m0 = (long)by * 256;
  const long n0 = (long)bx * 256;
  const int NT = K >> 6;

  int aBase[2], bBase[2];
  #pragma unroll
  for (int ks = 0; ks < 2; ++ks) {
    const int slot = (((ks * 4 + g) ^ L7) << 3);
    aBase[ks] = wr * 8192 + L15 * 64 + slot;
    bBase[ks] = 16384 + (wc >> 1) * 8192 + (wc & 1) * 4096 + L15 * 64 + slot;
  }

  const int rowoff = wid * 8 + (lane >> 3);
  const int colsw = ((lane & 7) ^ (lane >> 3)) << 3;   // u16
  const u16* Ag = A + m0 * ldk;
  const u16* Bg = Bm + n0 * ldk;
  u16* ldsW = ldsu + tid * 8;

  auto g1 = [&](int t, int mat, int r0) {
    if (t >= NT) return;
    const u16* src = (mat ? Bg : Ag) + (size_t)(r0 + rowoff) * ldk
                     + (size_t)t * 64 + colsw;
    gload_lds16(src, ldsW + (t & 1) * 32768 + mat * 16384 + (r0 >> 6) * 512 * 8);
  };

#define RD_B()                                                              \
  _Pragma("unroll") for (int j = 0; j < 4; ++j)                             \
    _Pragma("unroll") for (int ks = 0; ks < 2; ++ks)                        \
      bfr[j][ks] = __builtin_bit_cast(bf16x8,                               \
          *reinterpret_cast<const us8*>(&ldsu[bufOff + bBase[ks] + j * 1024]));
#define RD_A(q)                                                             \
  _Pragma("unroll") for (int t = 0; t < 2; ++t)                             \
    _Pragma("unroll") for (int ks = 0; ks < 2; ++ks)                        \
      afr[t][ks] = __builtin_bit_cast(bf16x8,                               \
          *reinterpret_cast<const us8*>(                                    \
              &ldsu[bufOff + aBase[ks] + (2 * (q) + t) * 1024]));
#define LGKM0()                                                             \
  asm volatile("s_waitcnt lgkmcnt(0)" ::: "memory");                        \
  __builtin_amdgcn_sched_barrier(0);
#define MM(p)                                                               \
  __builtin_amdgcn_s_setprio(1);                                            \
  _Pragma("unroll") for (int ks = 0; ks < 2; ++ks)                          \
    _Pragma("unroll") for (int t = 0; t < 2; ++t)                           \
      _Pragma("unroll") for (int j = 0; j < 4; ++j)                         \
        acc[2 * (p) + t][j] = __builtin_amdgcn_mfma_f32_16x16x32_bf16(      \
            afr[t][ks], bfr[j][ks], acc[2 * (p) + t][j], 0, 0, 0);          \
  __builtin_amdgcn_s_setprio(0);

  g1(0, 1, 0); g1(0, 1, 64); g1(0, 1, 128); g1(0, 1, 192);
  g1(0, 0, 0); g1(0, 0, 128); g1(0, 0, 64); g1(0, 0, 192);
  g1(1, 1, 0); g1(1, 1, 64);
  g1(1, 1, 128); g1(1, 1, 192);
  g1(1, 0, 0); g1(1, 0, 128);
  asm volatile("s_waitcnt vmcnt(6)" ::: "memory");
  __builtin_amdgcn_s_barrier();

  f32x4 acc[8][4] = {};

  for (int k = 0; k < NT; ++k) {
    const int bufOff = (k & 1) * 32768;
    bf16x8 bfr[4][2];

    { bf16x8 afr[2][2];
      g1(k + 1, 0, 64); g1(k + 1, 0, 192);
      RD_B(); RD_A(0);
      asm volatile("s_waitcnt lgkmcnt(8)" ::: "memory");
      __builtin_amdgcn_s_barrier();
      LGKM0(); MM(0);
    }
    { bf16x8 afr[2][2];
      RD_A(1);
      g1(k + 2, 1, 0); g1(k + 2, 1, 64);
      __builtin_amdgcn_s_barrier();
      LGKM0(); MM(1);
    }
    { bf16x8 afr[2][2];
      RD_A(2);
      g1(k + 2, 1, 128); g1(k + 2, 1, 192);
      __builtin_amdgcn_s_barrier();
      LGKM0(); MM(2);
    }
    { bf16x8 afr[2][2];
      RD_A(3);
      g1(k + 2, 0, 0); g1(k + 2, 0, 128);
      if (k < NT - 2) asm volatile("s_waitcnt vmcnt(6)" ::: "memory");
      else            asm volatile("s_waitcnt vmcnt(0)" ::: "memory");
      __builtin_amdgcn_s_barrier();
      LGKM0(); MM(3);
    }
  }
#undef RD_B
#undef RD_A
#undef LGKM0
#undef MM

  // epilogue: P~ = exp(acc*scale); row-sums via LDS scratch
  __builtin_amdgcn_s_barrier();
  float* lsum = reinterpret_cast<float*>(ldsu);   // [256][68] f32, padded
  #pragma unroll
  for (int i = 0; i < 8; ++i) {
    #pragma unroll
    for (int q = 0; q < 4; ++q) {
      const int rl = wr * 128 + i * 16 + g * 4 + q;
      const long row = m0 + rl;
      float rsum = 0.f;
      #pragma unroll
      for (int j = 0; j < 4; ++j) {
        float v = __expf(acc[i][j][q] * scale);
        rsum += v;
        Cb[row * (long)Ncols + n0 + wc * 64 + j * 16 + L15] = f2bf(v);
      }
      lsum[rl * 68 + wc * 16 + L15] = rsum;
    }
  }
  __builtin_amdgcn_s_barrier();
  {
    const int rl = tid >> 1, half = tid & 1;
    const float4* rp =
        reinterpret_cast<const float4*>(&lsum[rl * 68 + half * 32]);
    float s4 = 0.f;
    #pragma unroll
    for (int c = 0; c < 8; ++c) {
      float4 v = rp[c];
      s4 += (v.x + v.y) + (v.z + v.w);
    }
    s4 += __shfl_xor(s4, 1);
    if (half == 0) atomicAdd(&Cf[m0 + rl], s4);
  }
}

// ====== 128x128 NT bf16 PV GEMM — round-7 phases, 64 KiB LDS ====
__global__ __launch_bounds__(256, 2)
void k_pv128(const u16* __restrict__ A, const u16* __restrict__ Bm,
             const float* __restrict__ rowsum, float* __restrict__ out,
             int nbx, long ldk, int K) {
  extern __shared__ u16 ldsu[];   // 32768 u16 = 64 KiB: [buf2][mat2][8192]
  const int tid = threadIdx.x;
  const int lane = tid & 63, wid = tid >> 6;
  const int wr = wid >> 1, wc = wid & 1;
  const int L15 = lane & 15, L7 = lane & 7, g = lane >> 4;

  const int nwg = gridDim.x, bid = blockIdx.x;
  const int wg = ((nwg & 7) == 0) ? ((bid & 7) * (nwg >> 3) + (bid >> 3)) : bid;
  const int bx = wg % nbx, by = wg / nbx;
  const long m0 = (long)by * 128, n0 = (long)bx * 128;
  const int NT = K >> 6;

  int aBase[2], bBase[2];
  #pragma unroll
  for (int ks = 0; ks < 2; ++ks) {
    const int slot = (((ks * 4 + g) ^ L7) << 3);
    aBase[ks] = (wr * 64 + L15) * 64 + slot;
    bBase[ks] = 8192 + (wc * 64 + L15) * 64 + slot;
  }

  const int rowoff = tid >> 3;
  const int colsw = ((tid & 7) ^ ((tid >> 3) & 7)) << 3;
  const u16* Ag = A + m0 * ldk;
  const u16* Bg = Bm + n0 * ldk;
  u16* ldsW = ldsu + tid * 8;

  auto g1 = [&](int t, int mat, int r0) {
    if (t >= NT) return;
    const u16* src = (mat ? Bg : Ag) + (size_t)(r0 + rowoff) * ldk
                     + (size_t)t * 64 + colsw;
    gload_lds16(src, ldsW + (t & 1) * 16384 + mat * 8192 + r0 * 64);
  };

#define PLGKM0()                                                            \
  asm volatile("s_waitcnt lgkmcnt(0)" ::: "memory");                        \
  __builtin_amdgcn_sched_barrier(0);
#define PMM(p)                                                              \
  __builtin_amdgcn_s_setprio(1);                                            \
  _Pragma("unroll") for (int ks = 0; ks < 2; ++ks)                          \
    _Pragma("unroll") for (int j = 0; j < 4; ++j)                           \
      acc[p][j] = __builtin_amdgcn_mfma_f32_16x16x32_bf16(                  \
          afr[ks], bfr[j][ks], acc[p][j], 0, 0, 0);                         \
  __builtin_amdgcn_s_setprio(0);
#define PRD_A(q)                                                            \
  _Pragma("unroll") for (int ks = 0; ks < 2; ++ks)                          \
    afr[ks] = __builtin_bit_cast(bf16x8,                                    \
        *reinterpret_cast<const us8*>(&ldsu[bufOff + aBase[ks] + (q) * 1024]));

  g1(0, 1, 0); g1(0, 1, 32); g1(0, 1, 64); g1(0, 1, 96);
  g1(0, 0, 0); g1(0, 0, 32); g1(0, 0, 64); g1(0, 0, 96);
  g1(1, 1, 0); g1(1, 1, 32); g1(1, 1, 64); g1(1, 1, 96);
  g1(1, 0, 0); g1(1, 0, 32);
  asm volatile("s_waitcnt vmcnt(6)" ::: "memory");
  __builtin_amdgcn_s_barrier();

  f32x4 acc[4][4] = {};

  for (int k = 0; k < NT; ++k) {
    const int bufOff = (k & 1) * 16384;
    bf16x8 bfr[4][2];

    { bf16x8 afr[2];
      g1(k + 1, 0, 64); g1(k + 1, 0, 96);
      #pragma unroll
      for (int j = 0; j < 4; ++j)
        #pragma unroll
        for (int ks = 0; ks < 2; ++ks)
          bfr[j][ks] = __builtin_bit_cast(bf16x8,
              *reinterpret_cast<const us8*>(&ldsu[bufOff + bBase[ks] + j * 1024]));
      PRD_A(0);
      asm volatile("s_waitcnt lgkmcnt(8)" ::: "memory");
      __builtin_amdgcn_s_barrier();
      PLGKM0(); PMM(0);
    }
    { bf16x8 afr[2];
      PRD_A(1);
      g1(k + 2, 1, 0); g1(k + 2, 1, 32);
      __builtin_amdgcn_s_barrier();
      PLGKM0(); PMM(1);
    }
    { bf16x8 afr[2];
      PRD_A(2);
      g1(k + 2, 1, 64); g1(k + 2, 1, 96);
      __builtin_amdgcn_s_barrier();
      PLGKM0(); PMM(2);
    }
    { bf16x8 afr[2];
      PRD_A(3);
      g1(k + 2, 0, 0); g1(k + 2, 0, 32);
      if (k < NT - 2) asm volatile("s_waitcnt vmcnt(6)" ::: "memory");
      else            asm volatile("s_waitcnt vmcnt(0)" ::: "memory");
      __builtin_amdgcn_s_barrier();
      PLGKM0(); PMM(3);
    }
  }
#undef PLGKM0
#undef PMM
#undef PRD_A

  #pragma unroll
  for (int i = 0; i < 4; ++i) {
    #pragma unroll
    for (int q = 0; q < 4; ++q) {
      long row = m0 + wr * 64 + i * 16 + g * 4 + q;
      float inv = 1.0f / rowsum[row];
      #pragma unroll
      for (int j = 0; j < 4; ++j) {
        long col = n0 + wc * 64 + j * 16 + L15;
        out[row * D_ + col] = acc[i][j][q] * inv;
      }
    }
  }
}

// ---------- 128x128 projection GEMM: A f32 (reg-staged+converted), B bf16 ----
// Cb[row*768+col] = bf16( sum_k A[row,k]*B[col,k] + bias[col] )
// A staged via 2x float4 load -> cvt -> ds_write_b128 to SWIZZLED slot
// (write-side swizzle; global A read stays linear). B via pre-swizzled-source
// gload_lds (validated round 12, conflicts=0).
__global__ __launch_bounds__(256, 2)
void k_projf(const float* __restrict__ Af, const u16* __restrict__ Bm,
             u16* __restrict__ Cb, const float* __restrict__ bias, long K) {
  __shared__ u16 Al[128 * 64];
  __shared__ u16 Bl[128 * 64];
  const int tid = threadIdx.x;
  const int lane = tid & 63;
  const int wave = tid >> 6;
  const int wr = wave >> 1, wc = wave & 1;
  const int L15 = lane & 15, L7 = lane & 7, g = lane >> 4;
  const long m0 = (long)blockIdx.y * 128;
  const long n0 = (long)blockIdx.x * 128;

  f32x4 acc[4][4] = {};

  const int arow = tid >> 3;                 // 0..31
  const int acol = (tid & 7) * 8;            // linear global col chunk
  const int aswz = ((tid & 7) ^ ((tid >> 3) & 7)) * 8;  // swizzled LDS slot
  const u16* gB = Bm + (n0 + (tid >> 3)) * K + aswz;    // pre-swizzled source

  for (long kt = 0; kt < K; kt += 64) {
    __syncthreads();
    #pragma unroll
    for (int r = 0; r < 4; ++r) {
      const float* src = Af + (m0 + r * 32 + arow) * K + kt + acol;
      float4 v0 = *reinterpret_cast<const float4*>(src);
      float4 v1 = *reinterpret_cast<const float4*>(src + 4);
      us8 o;
      o[0] = f2bf(v0.x); o[1] = f2bf(v0.y); o[2] = f2bf(v0.z); o[3] = f2bf(v0.w);
      o[4] = f2bf(v1.x); o[5] = f2bf(v1.y); o[6] = f2bf(v1.z); o[7] = f2bf(v1.w);
      *reinterpret_cast<us8*>(&Al[(r * 32 + arow) * 64 + aswz]) = o;
      gload_lds16(gB + (size_t)(r * 32) * K + kt, &Bl[r * 2048 + tid * 8]);
    }
    __syncthreads();   // drains vmcnt+lgkm (compiler-inserted) + barrier
    #pragma unroll
    for (int ks = 0; ks < 2; ++ks) {
      const int slot = ((ks * 4 + g) ^ L7) * 8;
      bf16x8 av[4], bv[4];
      #pragma unroll
      for (int i = 0; i < 4; ++i) {
        av[i] = __builtin_bit_cast(bf16x8, *reinterpret_cast<const us8*>(
            &Al[(wr * 64 + i * 16 + L15) * 64 + slot]));
        bv[i] = __builtin_bit_cast(bf16x8, *reinterpret_cast<const us8*>(
            &Bl[(wc * 64 + i * 16 + L15) * 64 + slot]));
      }
      #pragma unroll
      for (int i = 0; i < 4; ++i)
        #pragma unroll
        for (int j = 0; j < 4; ++j)
          acc[i][j] = __builtin_amdgcn_mfma_f32_16x16x32_bf16(av[i], bv[j], acc[i][j], 0, 0, 0);
    }
  }

  #pragma unroll
  for (int i = 0; i < 4; ++i)
    #pragma unroll
    for (int q = 0; q < 4; ++q) {
      long row = m0 + wr * 64 + i * 16 + g * 4 + q;
      #pragma unroll
      for (int j = 0; j < 4; ++j) {
        long col = n0 + wc * 64 + j * 16 + L15;
        Cb[row * D_ + col] = f2bf(acc[i][j][q] + bias[col]);
      }
    }
}

extern "C" void kernel_launch(void* const* d_in, const int* in_sizes, int n_in,
                              void* d_out, int out_size, void* d_ws, size_t ws_size,
                              hipStream_t stream) {
  (void)in_sizes; (void)n_in; (void)out_size;
  const float* y     = (const float*)d_in[0];
  const float* Wy_w  = (const float*)d_in[1];
  const float* Wy_b  = (const float*)d_in[2];
  const float* Wz_w  = (const float*)d_in[3];
  const float* Wz_b  = (const float*)d_in[4];
  const float* dic   = (const float*)d_in[5];
  const float* prior = (const float*)d_in[6];
  float* out = (float*)d_out;

  hipFuncSetAttribute(reinterpret_cast<const void*>(&k_gemm8),
                      hipFuncAttributeMaxDynamicSharedMemorySize, 131072);
  hipFuncSetAttribute(reinterpret_cast<const void*>(&k_pv128),
                      hipFuncAttributeMaxDynamicSharedMemorySize, 65536);

  char* base = (char*)d_ws;
  size_t off = 0;
  auto alloc = [&](size_t bytes) -> char* {
    char* p = base + off;
    off = (off + bytes + 255) & ~(size_t)255;
    return p;
  };
  u16*  Wyb  = (u16*)alloc((size_t)D_ * D_ * 2);
  u16*  Wzb  = (u16*)alloc((size_t)D_ * D_ * 2);
  u16*  Qb   = (u16*)alloc((size_t)M_ * D_ * 2);
  u16*  Kb   = (u16*)alloc((size_t)N_ * D_ * 2);
  u16*  Vt   = (u16*)alloc((size_t)D_ * N_ * 2);
  float* rowsum = (float*)alloc((size_t)M_ * 4);
  size_t fixed = off;
  int Mc = M_;
  while (Mc > 256 && fixed + (size_t)Mc * N_ * 2 > ws_size) Mc >>= 1;
  u16* Sc = (u16*)alloc((size_t)Mc * N_ * 2);

  // zero row-sum accumulators (stream-ordered, capture-safe)
  hipMemsetAsync(rowsum, 0, (size_t)M_ * 4, stream);

  // both weights -> bf16 in one launch
  {
    int n4e = D_ * D_ / 4;
    int blocks = (2 * n4e + 255) / 256;
    if (blocks > 2048) blocks = 2048;
    hipLaunchKernelGGL(k_cvt2, dim3(blocks), dim3(256), 0, stream,
                       Wy_w, Wz_w, Wyb, Wzb, n4e);
  }

  // Vt = bf16(prior*dic^T)
  hipLaunchKernelGGL(k_build_vt, dim3(N_ / 32, D_ / 32), dim3(32, 8), 0, stream,
                     dic, prior, Vt);

  // Q = y * Wy^T + by ; K = dic * Wz^T + bz   (f32 A reg-staged, bf16 out)
  hipLaunchKernelGGL(k_projf, dim3(D_ / 128, M_ / 128), dim3(256), 0, stream,
                     y, Wyb, Qb, Wy_b, (long)D_);
  hipLaunchKernelGGL(k_projf, dim3(D_ / 128, N_ / 128), dim3(256), 0, stream,
                     dic, Wzb, Kb, Wz_b, (long)D_);

  const float scale = 0.036084391824351615f;  // 1/sqrt(768)
  for (int mc = 0; mc < M_; mc += Mc) {
    // P~ = exp(Q*K^T * scale) (bf16) + row-sums, fused into the S GEMM
    {
      const int nbx = N_ / 256, nby = Mc / 256;
      hipLaunchKernelGGL(k_gemm8, dim3(nbx * nby), dim3(512), 131072, stream,
                         Qb + (size_t)mc * D_, Kb, Sc, rowsum + mc, scale,
                         (long)D_, D_, N_, nbx);
    }
    // out = (P~ * Vt^T) / rowsum — phased 128^2 kernel
    {
      const int nbx = D_ / 128, nby = Mc / 128;   // 6 x 64 = 384 blocks
      hipLaunchKernelGGL(k_pv128, dim3(nbx * nby), dim3(256), 65536, stream,
                         Sc, Vt, rowsum + mc, out + (size_t)mc * D_,
                         nbx, (long)N_, N_);
    }
  }
}

// Round 16
// 287.567 us; speedup vs baseline: 1.0576x; 1.0576x over previous
//
#include <hip/hip_runtime.h>
#include <stdint.h>

#define M_ 8192   // B*L
#define D_ 768
#define N_ 8192

typedef unsigned short u16;
typedef __attribute__((ext_vector_type(8))) unsigned short us8;
typedef __attribute__((ext_vector_type(8))) __bf16 bf16x8;
typedef __attribute__((ext_vector_type(4))) float f32x4;

__device__ __forceinline__ u16 f2bf(float f) {
  uint32_t u = __builtin_bit_cast(uint32_t, f);
  u += 0x7FFFu + ((u >> 16) & 1u);   // RNE
  return (u16)(u >> 16);
}

__device__ __forceinline__ void gload_lds16(const void* g, void* l) {
  __builtin_amdgcn_global_load_lds(
      (__attribute__((address_space(1))) void*)g,
      (__attribute__((address_space(3))) void*)l, 16, 0, 0);
}

// ---------------- f32 -> bf16 convert (vectorized) ----------------
__global__ __launch_bounds__(256)
void k_cvt_bf16(const float* __restrict__ in, u16* __restrict__ out, int n4) {
  int stride = gridDim.x * blockDim.x;
  for (int i = blockIdx.x * blockDim.x + threadIdx.x; i < n4; i += stride) {
    float4 v = reinterpret_cast<const float4*>(in)[i];
    ushort4 o;
    o.x = f2bf(v.x); o.y = f2bf(v.y); o.z = f2bf(v.z); o.w = f2bf(v.w);
    reinterpret_cast<ushort4*>(out)[i] = o;
  }
}

// ------------- two-array f32 -> bf16 convert (both weights) -------------
__global__ __launch_bounds__(256)
void k_cvt2(const float* __restrict__ a, const float* __restrict__ b,
            u16* __restrict__ da, u16* __restrict__ db, int n4each) {
  int stride = gridDim.x * blockDim.x;
  for (int i = blockIdx.x * blockDim.x + threadIdx.x; i < 2 * n4each; i += stride) {
    const float* s = (i < n4each) ? a : b;
    u16* d = (i < n4each) ? da : db;
    int j = (i < n4each) ? i : i - n4each;
    float4 v = reinterpret_cast<const float4*>(s)[j];
    ushort4 o;
    o.x = f2bf(v.x); o.y = f2bf(v.y); o.z = f2bf(v.z); o.w = f2bf(v.w);
    reinterpret_cast<ushort4*>(d)[j] = o;
  }
}

// ---- fused: Db[n][d] = bf16(dic[n][d]);  Vt[d][n] = bf16(prior[n]*dic[n][d])
__global__ __launch_bounds__(256)
void k_build_vt(const float* __restrict__ dic, const float* __restrict__ prior,
                u16* __restrict__ Db, u16* __restrict__ Vt) {
  __shared__ float t[32][33];
  const int n0 = blockIdx.x * 32, d0 = blockIdx.y * 32;
  const int tx = threadIdx.x, ty = threadIdx.y;
  #pragma unroll
  for (int i = ty; i < 32; i += 8) {
    float v = dic[(size_t)(n0 + i) * D_ + d0 + tx];
    Db[(size_t)(n0 + i) * D_ + d0 + tx] = f2bf(v);
    t[i][tx] = v * prior[n0 + i];
  }
  __syncthreads();
  #pragma unroll
  for (int i = ty; i < 32; i += 8)
    Vt[(size_t)(d0 + i) * N_ + n0 + tx] = f2bf(t[tx][i]);
}

// ============ 256x256 NT bf16 S-GEMM — round-7 schedule (best measured) ====
// Cb = bf16(exp(acc*scale)), row-sums via LDS scratch -> 1 atomic/row/block.
__global__ __launch_bounds__(512, 2)
void k_gemm8(const u16* __restrict__ A, const u16* __restrict__ Bm,
             u16* __restrict__ Cb, float* __restrict__ Cf, float scale,
             long ldk, int K, int Ncols, int nbx) {
  extern __shared__ u16 ldsu[];   // 65536 u16 = 128 KiB: [buf2][mat2][16384]
  const int tid = threadIdx.x;
  const int lane = tid & 63, wid = tid >> 6;
  const int wr = wid >> 2, wc = wid & 3;
  const int L15 = lane & 15, L7 = lane & 7, g = lane >> 4;

  const int nwg = gridDim.x;
  const int bid = blockIdx.x;
  const int wg = ((nwg & 7) == 0) ? ((bid & 7) * (nwg >> 3) + (bid >> 3)) : bid;
  const int bx = wg % nbx, by = wg / nbx;
  const long m0 = (long)by * 256;
  const long n0 = (long)bx * 256;
  const int NT = K >> 6;

  int aBase[2], bBase[2];
  #pragma unroll
  for (int ks = 0; ks < 2; ++ks) {
    const int slot = (((ks * 4 + g) ^ L7) << 3);
    aBase[ks] = wr * 8192 + L15 * 64 + slot;
    bBase[ks] = 16384 + (wc >> 1) * 8192 + (wc & 1) * 4096 + L15 * 64 + slot;
  }

  const int rowoff = wid * 8 + (lane >> 3);
  const int colsw = ((lane & 7) ^ (lane >> 3)) << 3;   // u16
  const u16* Ag = A + m0 * ldk;
  const u16* Bg = Bm + n0 * ldk;
  u16* ldsW = ldsu + tid * 8;

  auto g1 = [&](int t, int mat, int r0) {
    if (t >= NT) return;
    const u16* src = (mat ? Bg : Ag) + (size_t)(r0 + rowoff) * ldk
                     + (size_t)t * 64 + colsw;
    gload_lds16(src, ldsW + (t & 1) * 32768 + mat * 16384 + (r0 >> 6) * 512 * 8);
  };

#define RD_B()                                                              \
  _Pragma("unroll") for (int j = 0; j < 4; ++j)                             \
    _Pragma("unroll") for (int ks = 0; ks < 2; ++ks)                        \
      bfr[j][ks] = __builtin_bit_cast(bf16x8,                               \
          *reinterpret_cast<const us8*>(&ldsu[bufOff + bBase[ks] + j * 1024]));
#define RD_A(q)                                                             \
  _Pragma("unroll") for (int t = 0; t < 2; ++t)                             \
    _Pragma("unroll") for (int ks = 0; ks < 2; ++ks)                        \
      afr[t][ks] = __builtin_bit_cast(bf16x8,                               \
          *reinterpret_cast<const us8*>(                                    \
              &ldsu[bufOff + aBase[ks] + (2 * (q) + t) * 1024]));
#define LGKM0()                                                             \
  asm volatile("s_waitcnt lgkmcnt(0)" ::: "memory");                        \
  __builtin_amdgcn_sched_barrier(0);
#define MM(p)                                                               \
  __builtin_amdgcn_s_setprio(1);                                            \
  _Pragma("unroll") for (int ks = 0; ks < 2; ++ks)                          \
    _Pragma("unroll") for (int t = 0; t < 2; ++t)                           \
      _Pragma("unroll") for (int j = 0; j < 4; ++j)                         \
        acc[2 * (p) + t][j] = __builtin_amdgcn_mfma_f32_16x16x32_bf16(      \
            afr[t][ks], bfr[j][ks], acc[2 * (p) + t][j], 0, 0, 0);          \
  __builtin_amdgcn_s_setprio(0);

  g1(0, 1, 0); g1(0, 1, 64); g1(0, 1, 128); g1(0, 1, 192);
  g1(0, 0, 0); g1(0, 0, 128); g1(0, 0, 64); g1(0, 0, 192);
  g1(1, 1, 0); g1(1, 1, 64);
  g1(1, 1, 128); g1(1, 1, 192);
  g1(1, 0, 0); g1(1, 0, 128);
  asm volatile("s_waitcnt vmcnt(6)" ::: "memory");
  __builtin_amdgcn_s_barrier();

  f32x4 acc[8][4] = {};

  for (int k = 0; k < NT; ++k) {
    const int bufOff = (k & 1) * 32768;
    bf16x8 bfr[4][2];

    { bf16x8 afr[2][2];
      g1(k + 1, 0, 64); g1(k + 1, 0, 192);
      RD_B(); RD_A(0);
      asm volatile("s_waitcnt lgkmcnt(8)" ::: "memory");
      __builtin_amdgcn_s_barrier();
      LGKM0(); MM(0);
    }
    { bf16x8 afr[2][2];
      RD_A(1);
      g1(k + 2, 1, 0); g1(k + 2, 1, 64);
      __builtin_amdgcn_s_barrier();
      LGKM0(); MM(1);
    }
    { bf16x8 afr[2][2];
      RD_A(2);
      g1(k + 2, 1, 128); g1(k + 2, 1, 192);
      __builtin_amdgcn_s_barrier();
      LGKM0(); MM(2);
    }
    { bf16x8 afr[2][2];
      RD_A(3);
      g1(k + 2, 0, 0); g1(k + 2, 0, 128);
      if (k < NT - 2) asm volatile("s_waitcnt vmcnt(6)" ::: "memory");
      else            asm volatile("s_waitcnt vmcnt(0)" ::: "memory");
      __builtin_amdgcn_s_barrier();
      LGKM0(); MM(3);
    }
  }
#undef RD_B
#undef RD_A
#undef LGKM0
#undef MM

  // epilogue: P~ = exp(acc*scale); row-sums via LDS scratch
  __builtin_amdgcn_s_barrier();
  float* lsum = reinterpret_cast<float*>(ldsu);   // [256][68] f32, padded
  #pragma unroll
  for (int i = 0; i < 8; ++i) {
    #pragma unroll
    for (int q = 0; q < 4; ++q) {
      const int rl = wr * 128 + i * 16 + g * 4 + q;
      const long row = m0 + rl;
      float rsum = 0.f;
      #pragma unroll
      for (int j = 0; j < 4; ++j) {
        float v = __expf(acc[i][j][q] * scale);
        rsum += v;
        Cb[row * (long)Ncols + n0 + wc * 64 + j * 16 + L15] = f2bf(v);
      }
      lsum[rl * 68 + wc * 16 + L15] = rsum;
    }
  }
  __builtin_amdgcn_s_barrier();
  {
    const int rl = tid >> 1, half = tid & 1;
    const float4* rp =
        reinterpret_cast<const float4*>(&lsum[rl * 68 + half * 32]);
    float s4 = 0.f;
    #pragma unroll
    for (int c = 0; c < 8; ++c) {
      float4 v = rp[c];
      s4 += (v.x + v.y) + (v.z + v.w);
    }
    s4 += __shfl_xor(s4, 1);
    if (half == 0) atomicAdd(&Cf[m0 + rl], s4);
  }
}

// ====== 128x128 NT bf16 PV GEMM — round-7 phases, 64 KiB LDS ====
__global__ __launch_bounds__(256, 2)
void k_pv128(const u16* __restrict__ A, const u16* __restrict__ Bm,
             const float* __restrict__ rowsum, float* __restrict__ out,
             int nbx, long ldk, int K) {
  extern __shared__ u16 ldsu[];   // 32768 u16 = 64 KiB: [buf2][mat2][8192]
  const int tid = threadIdx.x;
  const int lane = tid & 63, wid = tid >> 6;
  const int wr = wid >> 1, wc = wid & 1;
  const int L15 = lane & 15, L7 = lane & 7, g = lane >> 4;

  const int nwg = gridDim.x, bid = blockIdx.x;
  const int wg = ((nwg & 7) == 0) ? ((bid & 7) * (nwg >> 3) + (bid >> 3)) : bid;
  const int bx = wg % nbx, by = wg / nbx;
  const long m0 = (long)by * 128, n0 = (long)bx * 128;
  const int NT = K >> 6;

  int aBase[2], bBase[2];
  #pragma unroll
  for (int ks = 0; ks < 2; ++ks) {
    const int slot = (((ks * 4 + g) ^ L7) << 3);
    aBase[ks] = (wr * 64 + L15) * 64 + slot;
    bBase[ks] = 8192 + (wc * 64 + L15) * 64 + slot;
  }

  const int rowoff = tid >> 3;
  const int colsw = ((tid & 7) ^ ((tid >> 3) & 7)) << 3;
  const u16* Ag = A + m0 * ldk;
  const u16* Bg = Bm + n0 * ldk;
  u16* ldsW = ldsu + tid * 8;

  auto g1 = [&](int t, int mat, int r0) {
    if (t >= NT) return;
    const u16* src = (mat ? Bg : Ag) + (size_t)(r0 + rowoff) * ldk
                     + (size_t)t * 64 + colsw;
    gload_lds16(src, ldsW + (t & 1) * 16384 + mat * 8192 + r0 * 64);
  };

#define PLGKM0()                                                            \
  asm volatile("s_waitcnt lgkmcnt(0)" ::: "memory");                        \
  __builtin_amdgcn_sched_barrier(0);
#define PMM(p)                                                              \
  __builtin_amdgcn_s_setprio(1);                                            \
  _Pragma("unroll") for (int ks = 0; ks < 2; ++ks)                          \
    _Pragma("unroll") for (int j = 0; j < 4; ++j)                           \
      acc[p][j] = __builtin_amdgcn_mfma_f32_16x16x32_bf16(                  \
          afr[ks], bfr[j][ks], acc[p][j], 0, 0, 0);                         \
  __builtin_amdgcn_s_setprio(0);
#define PRD_A(q)                                                            \
  _Pragma("unroll") for (int ks = 0; ks < 2; ++ks)                          \
    afr[ks] = __builtin_bit_cast(bf16x8,                                    \
        *reinterpret_cast<const us8*>(&ldsu[bufOff + aBase[ks] + (q) * 1024]));

  g1(0, 1, 0); g1(0, 1, 32); g1(0, 1, 64); g1(0, 1, 96);
  g1(0, 0, 0); g1(0, 0, 32); g1(0, 0, 64); g1(0, 0, 96);
  g1(1, 1, 0); g1(1, 1, 32); g1(1, 1, 64); g1(1, 1, 96);
  g1(1, 0, 0); g1(1, 0, 32);
  asm volatile("s_waitcnt vmcnt(6)" ::: "memory");
  __builtin_amdgcn_s_barrier();

  f32x4 acc[4][4] = {};

  for (int k = 0; k < NT; ++k) {
    const int bufOff = (k & 1) * 16384;
    bf16x8 bfr[4][2];

    { bf16x8 afr[2];
      g1(k + 1, 0, 64); g1(k + 1, 0, 96);
      #pragma unroll
      for (int j = 0; j < 4; ++j)
        #pragma unroll
        for (int ks = 0; ks < 2; ++ks)
          bfr[j][ks] = __builtin_bit_cast(bf16x8,
              *reinterpret_cast<const us8*>(&ldsu[bufOff + bBase[ks] + j * 1024]));
      PRD_A(0);
      asm volatile("s_waitcnt lgkmcnt(8)" ::: "memory");
      __builtin_amdgcn_s_barrier();
      PLGKM0(); PMM(0);
    }
    { bf16x8 afr[2];
      PRD_A(1);
      g1(k + 2, 1, 0); g1(k + 2, 1, 32);
      __builtin_amdgcn_s_barrier();
      PLGKM0(); PMM(1);
    }
    { bf16x8 afr[2];
      PRD_A(2);
      g1(k + 2, 1, 64); g1(k + 2, 1, 96);
      __builtin_amdgcn_s_barrier();
      PLGKM0(); PMM(2);
    }
    { bf16x8 afr[2];
      PRD_A(3);
      g1(k + 2, 0, 0); g1(k + 2, 0, 32);
      if (k < NT - 2) asm volatile("s_waitcnt vmcnt(6)" ::: "memory");
      else            asm volatile("s_waitcnt vmcnt(0)" ::: "memory");
      __builtin_amdgcn_s_barrier();
      PLGKM0(); PMM(3);
    }
  }
#undef PLGKM0
#undef PMM
#undef PRD_A

  #pragma unroll
  for (int i = 0; i < 4; ++i) {
    #pragma unroll
    for (int q = 0; q < 4; ++q) {
      long row = m0 + wr * 64 + i * 16 + g * 4 + q;
      float inv = 1.0f / rowsum[row];
      #pragma unroll
      for (int j = 0; j < 4; ++j) {
        long col = n0 + wc * 64 + j * 16 + L15;
        out[row * D_ + col] = acc[i][j][q] * inv;
      }
    }
  }
}

// ---------- merged projection GEMM (both Q and K in one launch) ----------
// grid (D_/128, nby0+nby1); blocks with by<nby0 compute C0 = A0*Bm0^T + b0,
// the rest C1 = A1*Bm1^T + b1. T2-swizzled (conflicts=0, round 12).
__global__ __launch_bounds__(256, 2)
void k_proj(const u16* __restrict__ A0, const u16* __restrict__ A1,
            const u16* __restrict__ Bm0, const u16* __restrict__ Bm1,
            u16* __restrict__ C0, u16* __restrict__ C1,
            const float* __restrict__ b0, const float* __restrict__ b1,
            int nby0, long K) {
  __shared__ u16 Al[128 * 64];
  __shared__ u16 Bl[128 * 64];
  const int tid = threadIdx.x;
  const int lane = tid & 63;
  const int wave = tid >> 6;
  const int wr = wave >> 1, wc = wave & 1;
  const int L15 = lane & 15, L7 = lane & 7, g = lane >> 4;

  int by = blockIdx.y;
  const bool second = (by >= nby0);
  if (second) by -= nby0;
  const u16* A  = second ? A1 : A0;
  const u16* Bm = second ? Bm1 : Bm0;
  u16* Cb       = second ? C1 : C0;
  const float* bias = second ? b1 : b0;

  const long m0 = (long)by * 128;
  const long n0 = (long)blockIdx.x * 128;

  f32x4 acc[4][4] = {};

  const int colsw = ((tid & 7) ^ ((tid >> 3) & 7)) * 8;   // u16
  const u16* gA = A + (m0 + (tid >> 3)) * K + colsw;
  const u16* gB = Bm + (n0 + (tid >> 3)) * K + colsw;

  for (long kt = 0; kt < K; kt += 64) {
    __syncthreads();
    #pragma unroll
    for (int r = 0; r < 4; ++r) {
      gload_lds16(gA + (size_t)(r * 32) * K + kt, &Al[r * 2048 + tid * 8]);
      gload_lds16(gB + (size_t)(r * 32) * K + kt, &Bl[r * 2048 + tid * 8]);
    }
    __syncthreads();
    #pragma unroll
    for (int ks = 0; ks < 2; ++ks) {
      const int slot = ((ks * 4 + g) ^ L7) * 8;
      bf16x8 av[4], bv[4];
      #pragma unroll
      for (int i = 0; i < 4; ++i) {
        av[i] = __builtin_bit_cast(bf16x8, *reinterpret_cast<const us8*>(
            &Al[(wr * 64 + i * 16 + L15) * 64 + slot]));
        bv[i] = __builtin_bit_cast(bf16x8, *reinterpret_cast<const us8*>(
            &Bl[(wc * 64 + i * 16 + L15) * 64 + slot]));
      }
      #pragma unroll
      for (int i = 0; i < 4; ++i)
        #pragma unroll
        for (int j = 0; j < 4; ++j)
          acc[i][j] = __builtin_amdgcn_mfma_f32_16x16x32_bf16(av[i], bv[j], acc[i][j], 0, 0, 0);
    }
  }

  #pragma unroll
  for (int i = 0; i < 4; ++i)
    #pragma unroll
    for (int q = 0; q < 4; ++q) {
      long row = m0 + wr * 64 + i * 16 + g * 4 + q;
      #pragma unroll
      for (int j = 0; j < 4; ++j) {
        long col = n0 + wc * 64 + j * 16 + L15;
        Cb[row * D_ + col] = f2bf(acc[i][j][q] + bias[col]);
      }
    }
}

extern "C" void kernel_launch(void* const* d_in, const int* in_sizes, int n_in,
                              void* d_out, int out_size, void* d_ws, size_t ws_size,
                              hipStream_t stream) {
  (void)in_sizes; (void)n_in; (void)out_size;
  const float* y     = (const float*)d_in[0];
  const float* Wy_w  = (const float*)d_in[1];
  const float* Wy_b  = (const float*)d_in[2];
  const float* Wz_w  = (const float*)d_in[3];
  const float* Wz_b  = (const float*)d_in[4];
  const float* dic   = (const float*)d_in[5];
  const float* prior = (const float*)d_in[6];
  float* out = (float*)d_out;

  hipFuncSetAttribute(reinterpret_cast<const void*>(&k_gemm8),
                      hipFuncAttributeMaxDynamicSharedMemorySize, 131072);
  hipFuncSetAttribute(reinterpret_cast<const void*>(&k_pv128),
                      hipFuncAttributeMaxDynamicSharedMemorySize, 65536);

  char* base = (char*)d_ws;
  size_t off = 0;
  auto alloc = [&](size_t bytes) -> char* {
    char* p = base + off;
    off = (off + bytes + 255) & ~(size_t)255;
    return p;
  };
  u16*  Yb   = (u16*)alloc((size_t)M_ * D_ * 2);
  u16*  Db   = (u16*)alloc((size_t)N_ * D_ * 2);
  u16*  Wyb  = (u16*)alloc((size_t)D_ * D_ * 2);
  u16*  Wzb  = (u16*)alloc((size_t)D_ * D_ * 2);
  u16*  Qb   = (u16*)alloc((size_t)M_ * D_ * 2);
  u16*  Kb   = (u16*)alloc((size_t)N_ * D_ * 2);
  u16*  Vt   = (u16*)alloc((size_t)D_ * N_ * 2);
  float* rowsum = (float*)alloc((size_t)M_ * 4);
  size_t fixed = off;
  int Mc = M_;
  while (Mc > 256 && fixed + (size_t)Mc * N_ * 2 > ws_size) Mc >>= 1;
  u16* Sc = (u16*)alloc((size_t)Mc * N_ * 2);

  // zero row-sum accumulators (stream-ordered, capture-safe)
  hipMemsetAsync(rowsum, 0, (size_t)M_ * 4, stream);

  // y -> bf16
  {
    int n4 = M_ * D_ / 4;
    int blocks = (n4 + 255) / 256;
    if (blocks > 2048) blocks = 2048;
    hipLaunchKernelGGL(k_cvt_bf16, dim3(blocks), dim3(256), 0, stream, y, Yb, n4);
  }
  // both weights -> bf16 in one launch
  {
    int n4e = D_ * D_ / 4;
    int blocks = (2 * n4e + 255) / 256;
    if (blocks > 2048) blocks = 2048;
    hipLaunchKernelGGL(k_cvt2, dim3(blocks), dim3(256), 0, stream,
                       Wy_w, Wz_w, Wyb, Wzb, n4e);
  }

  // fused: Db = bf16(dic), Vt = bf16(prior*dic^T)
  hipLaunchKernelGGL(k_build_vt, dim3(N_ / 32, D_ / 32), dim3(32, 8), 0, stream,
                     dic, prior, Db, Vt);

  // Q = Yb*Wyb^T + by  AND  K = Db*Wzb^T + bz — single merged launch
  hipLaunchKernelGGL(k_proj, dim3(D_ / 128, M_ / 128 + N_ / 128), dim3(256), 0, stream,
                     Yb, Db, Wyb, Wzb, Qb, Kb, Wy_b, Wz_b, M_ / 128, (long)D_);

  const float scale = 0.036084391824351615f;  // 1/sqrt(768)
  for (int mc = 0; mc < M_; mc += Mc) {
    // P~ = exp(Q*K^T * scale) (bf16) + row-sums, fused into the S GEMM
    {
      const int nbx = N_ / 256, nby = Mc / 256;
      hipLaunchKernelGGL(k_gemm8, dim3(nbx * nby), dim3(512), 131072, stream,
                         Qb + (size_t)mc * D_, Kb, Sc, rowsum + mc, scale,
                         (long)D_, D_, N_, nbx);
    }
    // out = (P~ * Vt^T) / rowsum — phased 128^2 kernel
    {
      const int nbx = D_ / 128, nby = Mc / 128;   // 6 x 64 = 384 blocks
      hipLaunchKernelGGL(k_pv128, dim3(nbx * nby), dim3(256), 65536, stream,
                         Sc, Vt, rowsum + mc, out + (size_t)mc * D_,
                         nbx, (long)N_, N_);
    }
  }
}